// Round 7
// baseline (4818.042 us; speedup 1.0000x reference)
//
#include <hip/hip_runtime.h>
#include <hip/hip_bf16.h>

#define Vv 32000
#define Tz 256
#define Hz 256
#define RING 64
#define HST 264   // LDS h row stride in BYTES (fp8): 33 x 8B, odd slots -> low conflict

typedef __attribute__((ext_vector_type(8))) short short8;
typedef __attribute__((ext_vector_type(4))) float f32x4;

__device__ __forceinline__ float sigm(float x) { return 1.f / (1.f + __expf(-x)); }
__device__ __forceinline__ float tanh_(float x) {
    float e = __expf(2.f * x);
    return 1.f - 2.f / (e + 1.f);
}
__device__ __forceinline__ unsigned short f2bf(float x) {
    union { __hip_bfloat16 h; unsigned short u; } cv; cv.h = __float2bfloat16(x); return cv.u;
}
__device__ __forceinline__ float bf2f(unsigned short u) {
    union { unsigned u; float f; } cv; cv.u = ((unsigned)u) << 16; return cv.f;
}
__device__ __forceinline__ unsigned f2fp8(float x) {
    return ((unsigned)__builtin_amdgcn_cvt_pk_fp8_f32(x, x, 0, false)) & 0xffu;
}

// ---------- embedding gather -> xs_bf [T][B][256] bf16 (row = t*32+b)
__global__ __launch_bounds__(64) void k_embed(const int* __restrict__ inp,
    const float* __restrict__ emb, __hip_bfloat16* __restrict__ xs) {
    int row = blockIdx.x;
    int t = row >> 5, b = row & 31;
    const float* src = emb + (size_t)inp[b * Tz + t] * Hz;
    int tid = threadIdx.x;
    float4 v = *(const float4*)&src[tid * 4];
    __hip_bfloat16* dst = xs + (size_t)row * Hz + tid * 4;
    dst[0] = __float2bfloat16(v.x); dst[1] = __float2bfloat16(v.y);
    dst[2] = __float2bfloat16(v.z); dst[3] = __float2bfloat16(v.w);
}

// ---------- W [512 k][1024 zc] f32 -> gate-grouped: gi = hid*4+gate (zc = gate*256+hid).
// W1 k<256  -> W1xG bf16 [1024 gi][256 k]   (x-part of layer1, used by k_xw GEMM)
// W1 k>=256 -> W1hG fp8  [1024][256]
// W2 k<256  -> W2xG fp8;  W2 k>=256 -> W2hG fp8
__global__ __launch_bounds__(256) void k_wt(const float* __restrict__ W1,
    const float* __restrict__ W2, unsigned short* __restrict__ W1xG,
    unsigned char* __restrict__ W1hG, unsigned char* __restrict__ W2xG,
    unsigned char* __restrict__ W2hG)
{
    __shared__ float tile[64][65];
    int bid = blockIdx.x;              // 256 blocks: layer x 8 ktiles x 16 zctiles
    int layer = bid >> 7;
    int tl = bid & 127;
    int kt = tl & 7, zt = tl >> 3;
    int k0 = kt * 64, zc0 = zt * 64;
    int gate = zt >> 2, hid0 = (zt & 3) * 64;
    const float* W = layer ? W2 : W1;
    int tid = threadIdx.x;
#pragma unroll
    for (int p = 0; p < 16; ++p) {
        int lin = p * 256 + tid;
        int kk = lin >> 6, zz = lin & 63;
        tile[kk][zz] = W[(size_t)(k0 + kk) * 1024 + zc0 + zz];
    }
    __syncthreads();
    int kb = k0 & 255;
    if (!layer && k0 < 256) {
#pragma unroll
        for (int p = 0; p < 16; ++p) {
            int lin = p * 256 + tid;
            int zz = lin >> 6, kk = lin & 63;
            int gi = (hid0 + zz) * 4 + gate;
            W1xG[(size_t)gi * 256 + kb + kk] = f2bf(tile[kk][zz]);
        }
    } else {
        unsigned char* dst = layer ? ((k0 < 256) ? W2xG : W2hG) : W1hG;
#pragma unroll
        for (int p = 0; p < 4; ++p) {
            int lin = p * 256 + tid;
            int zz = lin >> 4, kg = lin & 15;
            int gi = (hid0 + zz) * 4 + gate;
            unsigned r = (unsigned)__builtin_amdgcn_cvt_pk_fp8_f32(
                tile[kg * 4 + 0][zz], tile[kg * 4 + 1][zz], 0, false);
            r = (unsigned)__builtin_amdgcn_cvt_pk_fp8_f32(
                tile[kg * 4 + 2][zz], tile[kg * 4 + 3][zz], (int)r, true);
            *(unsigned*)&dst[(size_t)gi * 256 + kb + kg * 4] = r;
        }
    }
}

// ---------- z1x precompute: XS[8192][256] @ W1xG^T (+b1) -> z1xG [8192][1024 gi] bf16
__global__ __launch_bounds__(256) void k_xw(const __hip_bfloat16* __restrict__ Abf,
    const unsigned short* __restrict__ Bg, const float* __restrict__ b1v,
    unsigned short* __restrict__ outG)
{
    __shared__ __align__(16) unsigned short As[128 * 64];
    __shared__ __align__(16) unsigned short Bs[128 * 64];
    int tid = threadIdx.x;
    size_t r0 = (size_t)blockIdx.x * 128;
    size_t c0 = (size_t)blockIdx.y * 128;
    int l = tid & 63, w = tid >> 6, lr = l & 15, lk = l >> 4;
    f32x4 acc[2][8];
#pragma unroll
    for (int m = 0; m < 2; ++m)
#pragma unroll
        for (int f = 0; f < 8; ++f) acc[m][f] = (f32x4){0.f, 0.f, 0.f, 0.f};
    const unsigned short* A = (const unsigned short*)Abf;
    for (int kt = 0; kt < 4; ++kt) {
#pragma unroll
        for (int i = 0; i < 4; ++i) {
            int fi = i * 256 + tid;
            int row = fi >> 3, seg = fi & 7;
            int dseg = seg ^ (row & 7);
            *(short8*)&As[row * 64 + dseg * 8] =
                *(const short8*)&A[(r0 + row) * 256 + kt * 64 + seg * 8];
            *(short8*)&Bs[row * 64 + dseg * 8] =
                *(const short8*)&Bg[((size_t)c0 + row) * 256 + kt * 64 + seg * 8];
        }
        __syncthreads();
#pragma unroll
        for (int ks = 0; ks < 2; ++ks) {
            short8 a[2];
#pragma unroll
            for (int m = 0; m < 2; ++m) {
                int row = w * 32 + m * 16 + lr;
                a[m] = *(const short8*)&As[row * 64 + ((ks * 4 + lk) ^ (row & 7)) * 8];
            }
#pragma unroll
            for (int f = 0; f < 8; ++f) {
                int row = f * 16 + lr;
                short8 bfr = *(const short8*)&Bs[row * 64 + ((ks * 4 + lk) ^ (row & 7)) * 8];
#pragma unroll
                for (int m = 0; m < 2; ++m)
                    acc[m][f] = __builtin_amdgcn_mfma_f32_16x16x32_bf16(a[m], bfr, acc[m][f], 0, 0, 0);
            }
        }
        __syncthreads();
    }
#pragma unroll
    for (int f = 0; f < 8; ++f) {
        int gi = (int)c0 + f * 16 + lr;
        float bb = b1v[(gi & 3) * 256 + (gi >> 2)];
#pragma unroll
        for (int m = 0; m < 2; ++m)
#pragma unroll
            for (int j = 0; j < 4; ++j)
                outG[(r0 + w * 32 + m * 16 + lk * 4 + j) * 1024 + gi] =
                    f2bf(acc[m][f][j] + bb);
    }
}

// ---------- persistent 3-stage LSTM pipeline, fp8 weights in VGPRs, 1 CU per stage.
// bid0 = A: h1 recurrence (K=256, addend z1x).  bid1 = B: z2x = h1@W2x (+b2).
// bid2 = C: h2 recurrence (K=256, addend z2x).  bid>=3: softmax_w transpose.
// All cross-block edges forward-only. Publish = relaxed agent atomics (device-coherent),
// drained by __syncthreads' vmcnt(0), then relaxed atomic flag. No release/acquire fences.
__global__ __launch_bounds__(512, 2) void k_lstm5(
    const unsigned short* __restrict__ z1xG,    // [8192][1024] bf16
    const unsigned char*  __restrict__ W1hG,    // [1024][256] fp8
    const unsigned char*  __restrict__ W2xG,
    const unsigned char*  __restrict__ W2hG,
    const float* __restrict__ b2v,
    unsigned char*  __restrict__ h1hist,        // [256][32][256] fp8
    unsigned short* __restrict__ z2x,           // ring [RING][32][1024] bf16
    unsigned short* __restrict__ houtB,         // [8192][256] bf16 (row = b*256+t)
    unsigned* __restrict__ flags,               // fA=flags[0], fB=[16], fC=[32]
    const float* __restrict__ sw, __hip_bfloat16* __restrict__ swt)
{
    __shared__ __align__(16) unsigned char hl[32 * HST];
    __shared__ float tile[64][65];
    int bid = blockIdx.x, tid = threadIdx.x;

    if (bid >= 3) {        // folded softmax_w transpose (29 blocks)
        int idx = bid - 3;
        for (int tl = idx; tl < 2000; tl += 29) {
            int kt = tl & 3, vt = tl >> 2;
            int k0 = kt * 64, v0 = vt * 64;
#pragma unroll
            for (int pp = 0; pp < 8; ++pp) {
                int lin = pp * 512 + tid;
                int kk = lin >> 6, vv = lin & 63;
                tile[kk][vv] = sw[(size_t)(k0 + kk) * Vv + v0 + vv];
            }
            __syncthreads();
#pragma unroll
            for (int pp = 0; pp < 8; ++pp) {
                int lin = pp * 512 + tid;
                int vv = lin >> 6, kk = lin & 63;
                swt[(size_t)(v0 + vv) * 256 + k0 + kk] = __float2bfloat16(tile[kk][vv]);
            }
            __syncthreads();
        }
        return;
    }

    int role = bid;
    int w = tid >> 6, l = tid & 63, lr = l & 15, lk = l >> 4;
    const unsigned char* WG = (role == 0) ? W1hG : (role == 1) ? W2xG : W2hG;

    // weight fragments: 64 x 8B = 128 VGPR/lane. Frag slot j = k = kc*32+lk*8+j
    // (same packing used for the h operand -> any bijective k-map is consistent).
    long Wf[8][8];
#pragma unroll
    for (int hbl = 0; hbl < 8; ++hbl)
#pragma unroll
        for (int kc = 0; kc < 8; ++kc)
            Wf[hbl][kc] = *(const long*)&WG[(size_t)(((w * 8 + hbl) * 16 + lr) * 256 + kc * 32 + lk * 8)];

    for (int u = tid; u < 32 * HST / 4; u += 512) ((unsigned*)hl)[u] = 0u;  // h(-1)=0

    float c_[8][2];
#pragma unroll
    for (int i = 0; i < 8; ++i) { c_[i][0] = 0.f; c_[i][1] = 0.f; }
    f32x4 b2q[8];
    if (role == 1) {
#pragma unroll
        for (int hbl = 0; hbl < 8; ++hbl) {
            int hidl = (w * 8 + hbl) * 4 + lk;
#pragma unroll
            for (int j = 0; j < 4; ++j) b2q[hbl][j] = b2v[j * 256 + hidl];
        }
    }
    unsigned cach1 = 0, cach2 = 0;
    unsigned* fA = &flags[0]; unsigned* fB = &flags[16]; unsigned* fC = &flags[32];
    __syncthreads();

    for (int t = 0; t < 256; ++t) {
        if (role == 0) {
            // ---- stage A: z = W1h·h1(t-1) + z1x(t); h1(t) -> LDS + publish
            uint2 ad[8][2];
#pragma unroll
            for (int hbl = 0; hbl < 8; ++hbl)
#pragma unroll
                for (int bh = 0; bh < 2; ++bh)
                    ad[hbl][bh] = *(const uint2*)&z1xG[((size_t)(t * 32 + bh * 16 + lr)) * 1024 + (w * 8 + hbl) * 16 + lk * 4];
            unsigned pkv[2][8];
#pragma unroll
            for (int bh = 0; bh < 2; ++bh) {
                f32x4 acc[8];
#pragma unroll
                for (int hbl = 0; hbl < 8; ++hbl) acc[hbl] = (f32x4){0.f, 0.f, 0.f, 0.f};
#pragma unroll
                for (int kc = 0; kc < 8; ++kc) {
                    long hf = *(const long*)&hl[(bh * 16 + lr) * HST + kc * 32 + lk * 8];
#pragma unroll
                    for (int hbl = 0; hbl < 8; ++hbl)
                        acc[hbl] = __builtin_amdgcn_mfma_f32_16x16x32_fp8_fp8(Wf[hbl][kc], hf, acc[hbl], 0, 0, 0);
                }
#pragma unroll
                for (int hbl = 0; hbl < 8; ++hbl) {
                    float zi = acc[hbl][0] + bf2f((unsigned short)(ad[hbl][bh].x & 0xffff));
                    float zj = acc[hbl][1] + bf2f((unsigned short)(ad[hbl][bh].x >> 16));
                    float zf = acc[hbl][2] + bf2f((unsigned short)(ad[hbl][bh].y & 0xffff));
                    float zo = acc[hbl][3] + bf2f((unsigned short)(ad[hbl][bh].y >> 16));
                    float cn = c_[hbl][bh] * sigm(zf + 1.f) + sigm(zi) * tanh_(zj);
                    c_[hbl][bh] = cn;
                    float hv = tanh_(cn) * sigm(zo);
                    unsigned x = f2fp8(hv) << (lk * 8);
                    x |= __shfl_xor(x, 16); x |= __shfl_xor(x, 32);   // pack hid0..hid0+3
                    pkv[bh][hbl] = x;
                }
            }
            __syncthreads();   // all MFMA reads of h(t-1) done
            if (lk == 0) {
#pragma unroll
                for (int bh = 0; bh < 2; ++bh)
#pragma unroll
                    for (int hbl = 0; hbl < 8; ++hbl) {
                        int ba = bh * 16 + lr, hb = (w * 8 + hbl) * 4;
                        *(unsigned*)&hl[ba * HST + hb] = pkv[bh][hbl];
                        __hip_atomic_store((unsigned*)&h1hist[(size_t)t * 8192 + ba * 256 + hb],
                                           pkv[bh][hbl], __ATOMIC_RELAXED, __HIP_MEMORY_SCOPE_AGENT);
                    }
            }
            __syncthreads();   // drains vmcnt(0): publishes complete at coherence point
            if (tid == 0)
                __hip_atomic_store(fA, (unsigned)(t + 1), __ATOMIC_RELAXED, __HIP_MEMORY_SCOPE_AGENT);
        } else if (role == 1) {
            // ---- stage B: z2x(t) = W2x·h1(t) + b2 -> ring
            while (cach1 < (unsigned)(t + 1)) {
                cach1 = __hip_atomic_load(fA, __ATOMIC_RELAXED, __HIP_MEMORY_SCOPE_AGENT);
                if (cach1 < (unsigned)(t + 1)) __builtin_amdgcn_s_sleep(1);
            }
            if (t >= RING) {
                while (cach2 < (unsigned)(t - RING + 1)) {
                    cach2 = __hip_atomic_load(fC, __ATOMIC_RELAXED, __HIP_MEMORY_SCOPE_AGENT);
                    if (cach2 < (unsigned)(t - RING + 1)) __builtin_amdgcn_s_sleep(1);
                }
            }
            {   // stage h1(t): plain loads (first touch of these addresses this launch)
                int ba = tid >> 4, sg = tid & 15;
                uint4 g = *(const uint4*)&h1hist[(size_t)t * 8192 + ba * 256 + sg * 16];
                *(uint4*)&hl[ba * HST + sg * 16] = g;
            }
            __syncthreads();
            int ts = t & (RING - 1);
#pragma unroll
            for (int bh = 0; bh < 2; ++bh) {
                f32x4 acc[8];
#pragma unroll
                for (int hbl = 0; hbl < 8; ++hbl) acc[hbl] = (f32x4){0.f, 0.f, 0.f, 0.f};
#pragma unroll
                for (int kc = 0; kc < 8; ++kc) {
                    long hf = *(const long*)&hl[(bh * 16 + lr) * HST + kc * 32 + lk * 8];
#pragma unroll
                    for (int hbl = 0; hbl < 8; ++hbl)
                        acc[hbl] = __builtin_amdgcn_mfma_f32_16x16x32_fp8_fp8(Wf[hbl][kc], hf, acc[hbl], 0, 0, 0);
                }
#pragma unroll
                for (int hbl = 0; hbl < 8; ++hbl) {
                    f32x4 z = acc[hbl] + b2q[hbl];
                    unsigned lo = (unsigned)f2bf(z[0]) | ((unsigned)f2bf(z[1]) << 16);
                    unsigned hi = (unsigned)f2bf(z[2]) | ((unsigned)f2bf(z[3]) << 16);
                    unsigned long long v = (unsigned long long)lo | ((unsigned long long)hi << 32);
                    __hip_atomic_store((unsigned long long*)&z2x[((size_t)ts * 32 + bh * 16 + lr) * 1024 + (w * 8 + hbl) * 16 + lk * 4],
                                       v, __ATOMIC_RELAXED, __HIP_MEMORY_SCOPE_AGENT);
                }
            }
            __syncthreads();   // drain before flag
            if (tid == 0)
                __hip_atomic_store(fB, (unsigned)(t + 1), __ATOMIC_RELAXED, __HIP_MEMORY_SCOPE_AGENT);
        } else {
            // ---- stage C: z = W2h·h2(t-1) + z2x(t); h2(t) -> LDS + HoutB
            while (cach1 < (unsigned)(t + 1)) {
                cach1 = __hip_atomic_load(fB, __ATOMIC_RELAXED, __HIP_MEMORY_SCOPE_AGENT);
                if (cach1 < (unsigned)(t + 1)) __builtin_amdgcn_s_sleep(1);
            }
            int ts = t & (RING - 1);
            unsigned long long ad[8][2];   // atomic loads: ring addresses are reused -> bypass stale L1/L2
#pragma unroll
            for (int hbl = 0; hbl < 8; ++hbl)
#pragma unroll
                for (int bh = 0; bh < 2; ++bh)
                    ad[hbl][bh] = __hip_atomic_load(
                        (const unsigned long long*)&z2x[((size_t)ts * 32 + bh * 16 + lr) * 1024 + (w * 8 + hbl) * 16 + lk * 4],
                        __ATOMIC_RELAXED, __HIP_MEMORY_SCOPE_AGENT);
            unsigned pkv[2][8], pbf[2][8];
#pragma unroll
            for (int bh = 0; bh < 2; ++bh) {
                f32x4 acc[8];
#pragma unroll
                for (int hbl = 0; hbl < 8; ++hbl) acc[hbl] = (f32x4){0.f, 0.f, 0.f, 0.f};
#pragma unroll
                for (int kc = 0; kc < 8; ++kc) {
                    long hf = *(const long*)&hl[(bh * 16 + lr) * HST + kc * 32 + lk * 8];
#pragma unroll
                    for (int hbl = 0; hbl < 8; ++hbl)
                        acc[hbl] = __builtin_amdgcn_mfma_f32_16x16x32_fp8_fp8(Wf[hbl][kc], hf, acc[hbl], 0, 0, 0);
                }
#pragma unroll
                for (int hbl = 0; hbl < 8; ++hbl) {
                    unsigned adx = (unsigned)(ad[hbl][bh] & 0xffffffffu);
                    unsigned ady = (unsigned)(ad[hbl][bh] >> 32);
                    float zi = acc[hbl][0] + bf2f((unsigned short)(adx & 0xffff));
                    float zj = acc[hbl][1] + bf2f((unsigned short)(adx >> 16));
                    float zf = acc[hbl][2] + bf2f((unsigned short)(ady & 0xffff));
                    float zo = acc[hbl][3] + bf2f((unsigned short)(ady >> 16));
                    float cn = c_[hbl][bh] * sigm(zf + 1.f) + sigm(zi) * tanh_(zj);
                    c_[hbl][bh] = cn;
                    float hv = tanh_(cn) * sigm(zo);
                    unsigned x = f2fp8(hv) << (lk * 8);
                    x |= __shfl_xor(x, 16); x |= __shfl_xor(x, 32);
                    pkv[bh][hbl] = x;
                    unsigned y = ((unsigned)f2bf(hv)) << ((lk & 1) * 16);
                    y |= __shfl_xor(y, 16);
                    pbf[bh][hbl] = y;
                }
            }
            __syncthreads();   // MFMA reads of h2(t-1) done; ring loads consumed
            if (tid == 0)
                __hip_atomic_store(fC, (unsigned)(t + 1), __ATOMIC_RELAXED, __HIP_MEMORY_SCOPE_AGENT);
#pragma unroll
            for (int bh = 0; bh < 2; ++bh)
#pragma unroll
                for (int hbl = 0; hbl < 8; ++hbl) {
                    int ba = bh * 16 + lr, hb = (w * 8 + hbl) * 4;
                    if (lk == 0) *(unsigned*)&hl[ba * HST + hb] = pkv[bh][hbl];
                    if ((lk & 1) == 0)
                        *(unsigned*)&houtB[((size_t)(ba * 256 + t)) * 256 + hb + lk] = pbf[bh][hbl];
                }
            __syncthreads();   // h2(t) in LDS before next step
        }
    }
}

// ---------- logits GEMM: 128x128 tile, BK=64, XOR-swizzled LDS, streaming sum-of-exp
__global__ __launch_bounds__(256) void k_gemm(const __hip_bfloat16* __restrict__ Abf,
    const __hip_bfloat16* __restrict__ Bbf, const float* __restrict__ sb,
    float* __restrict__ row_sum)
{
    __shared__ __align__(16) unsigned short As[128 * 64];
    __shared__ __align__(16) unsigned short Bs[128 * 64];
    int tid = threadIdx.x;
    size_t r0 = (size_t)blockIdx.x * 128;
    size_t c0 = (size_t)blockIdx.y * 128;
    int l = tid & 63, w = tid >> 6, lr = l & 15, lk = l >> 4;

    f32x4 acc[2][8];
#pragma unroll
    for (int m = 0; m < 2; ++m)
#pragma unroll
        for (int f = 0; f < 8; ++f) acc[m][f] = (f32x4){0.f, 0.f, 0.f, 0.f};

    const unsigned short* A = (const unsigned short*)Abf;
    const unsigned short* B = (const unsigned short*)Bbf;

    for (int kt = 0; kt < 4; ++kt) {
#pragma unroll
        for (int i = 0; i < 4; ++i) {
            int fi = i * 256 + tid;
            int row = fi >> 3, seg = fi & 7;
            int dseg = seg ^ (row & 7);
            *(short8*)&As[row * 64 + dseg * 8] =
                *(const short8*)&A[(r0 + row) * 256 + kt * 64 + seg * 8];
            *(short8*)&Bs[row * 64 + dseg * 8] =
                *(const short8*)&B[(c0 + row) * 256 + kt * 64 + seg * 8];
        }
        __syncthreads();
#pragma unroll
        for (int ks = 0; ks < 2; ++ks) {
            short8 a[2];
#pragma unroll
            for (int m = 0; m < 2; ++m) {
                int row = w * 32 + m * 16 + lr;
                a[m] = *(const short8*)&As[row * 64 + ((ks * 4 + lk) ^ (row & 7)) * 8];
            }
#pragma unroll
            for (int f = 0; f < 8; ++f) {
                int row = f * 16 + lr;
                short8 bfr = *(const short8*)&Bs[row * 64 + ((ks * 4 + lk) ^ (row & 7)) * 8];
#pragma unroll
                for (int m = 0; m < 2; ++m)
                    acc[m][f] = __builtin_amdgcn_mfma_f32_16x16x32_bf16(a[m], bfr, acc[m][f], 0, 0, 0);
            }
        }
        __syncthreads();
    }

    float sums[2][4] = {{0.f,0.f,0.f,0.f},{0.f,0.f,0.f,0.f}};
#pragma unroll
    for (int f = 0; f < 8; ++f) {
        float sbv = sb[c0 + f * 16 + lr];
#pragma unroll
        for (int m = 0; m < 2; ++m)
#pragma unroll
            for (int j = 0; j < 4; ++j) sums[m][j] += __expf(acc[m][f][j] + sbv);
    }
#pragma unroll
    for (int msk = 1; msk <= 8; msk <<= 1)
#pragma unroll
        for (int m = 0; m < 2; ++m)
#pragma unroll
            for (int j = 0; j < 4; ++j) sums[m][j] += __shfl_xor(sums[m][j], msk);
    if (lr == 0) {
#pragma unroll
        for (int m = 0; m < 2; ++m)
#pragma unroll
            for (int j = 0; j < 4; ++j)
                atomicAdd(&row_sum[r0 + w * 32 + m * 16 + lk * 4 + j], sums[m][j]);
    }
}

// ---------- per-row loss: log(sum_exp) - target logit
__global__ __launch_bounds__(256) void k_loss(const __hip_bfloat16* __restrict__ houtB,
    const __hip_bfloat16* __restrict__ swt, const float* __restrict__ sb,
    const int* __restrict__ tgts, const float* __restrict__ row_sum,
    float* __restrict__ out)
{
    int r = blockIdx.x * 256 + threadIdx.x;
    int tg = tgts[r];
    const unsigned short* h = (const unsigned short*)houtB + (size_t)r * Hz;
    const unsigned short* wp = (const unsigned short*)swt + (size_t)tg * Hz;
    float acc = 0.f;
#pragma unroll 4
    for (int k8 = 0; k8 < 32; ++k8) {
        short8 hv = *(const short8*)&h[k8 * 8];
        short8 wv = *(const short8*)&wp[k8 * 8];
#pragma unroll
        for (int e = 0; e < 8; ++e)
            acc += bf2f((unsigned short)hv[e]) * bf2f((unsigned short)wv[e]);
    }
    float loss = logf(row_sum[r]) - (acc + sb[tg]);
#pragma unroll
    for (int m = 1; m < 64; m <<= 1) loss += __shfl_xor(loss, m);
    __shared__ float red[4];
    int l = threadIdx.x & 63, wvv = threadIdx.x >> 6;
    if (l == 0) red[wvv] = loss;
    __syncthreads();
    if (threadIdx.x == 0) {
        float s = red[0] + red[1] + red[2] + red[3];
        atomicAdd(out, s * (1.f / 8192.f));
    }
}

extern "C" void kernel_launch(void* const* d_in, const int* in_sizes, int n_in,
                              void* d_out, int out_size, void* d_ws, size_t ws_size,
                              hipStream_t stream)
{
    const int*   inp = (const int*)d_in[0];
    const int*   tgt = (const int*)d_in[1];
    const float* emb = (const float*)d_in[2];
    const float* W1  = (const float*)d_in[3];
    const float* b1  = (const float*)d_in[4];
    const float* W2  = (const float*)d_in[5];
    const float* b2  = (const float*)d_in[6];
    const float* sw  = (const float*)d_in[7];
    const float* sb  = (const float*)d_in[8];
    float* out = (float*)d_out;

    char* ws = (char*)d_ws;
    size_t off = 0;
    __hip_bfloat16* SWT  = (__hip_bfloat16*)(ws + off); off += (size_t)Vv * Hz * 2;        // 16,384,000
    __hip_bfloat16* XS   = (__hip_bfloat16*)(ws + off); off += (size_t)Tz * 32 * Hz * 2;   //  4,194,304
    unsigned short* W1xG = (unsigned short*)(ws + off); off += (size_t)1024 * 256 * 2;     //    524,288
    unsigned char*  W1hG = (unsigned char*)(ws + off);  off += (size_t)1024 * 256;         //    262,144
    unsigned char*  W2xG = (unsigned char*)(ws + off);  off += (size_t)1024 * 256;         //    262,144
    unsigned char*  W2hG = (unsigned char*)(ws + off);  off += (size_t)1024 * 256;         //    262,144
    unsigned short* Z1xG = (unsigned short*)(ws + off); off += (size_t)8192 * 1024 * 2;    // 16,777,216
    unsigned short* Z2X  = (unsigned short*)(ws + off); off += (size_t)RING * 32 * 1024 * 2; // 4,194,304
    unsigned char*  H1h  = (unsigned char*)(ws + off);  off += (size_t)Tz * 8192;          //  2,097,152
    unsigned short* HoutB= (unsigned short*)(ws + off); off += (size_t)8192 * Hz * 2;      //  4,194,304
    float* row_sum       = (float*)(ws + off);          off += 8192 * 4;                   //     32,768
    unsigned* flags      = (unsigned*)(ws + off);       off += 64 * 4;                     //        256
    // total ~49.2 MiB

    hipMemsetAsync(row_sum, 0, 8192 * 4 + 64 * 4, stream);   // row_sum + flags
    hipMemsetAsync(out, 0, sizeof(float), stream);

    k_embed<<<8192, 64, 0, stream>>>(inp, emb, XS);
    k_wt<<<256, 256, 0, stream>>>(W1, W2, W1xG, W1hG, W2xG, W2hG);
    k_xw<<<dim3(64, 8), 256, 0, stream>>>(XS, W1xG, b1, Z1xG);
    k_lstm5<<<32, 512, 0, stream>>>(Z1xG, W1hG, W2xG, W2hG, b2,
                                    H1h, Z2X, HoutB, flags, sw, SWT);
    k_gemm<<<dim3(64, 250), 256, 0, stream>>>((const __hip_bfloat16*)HoutB, SWT, sb, row_sum);
    k_loss<<<32, 256, 0, stream>>>((const __hip_bfloat16*)HoutB, SWT, sb, tgt, row_sum, out);
}

// Round 8
// 4051.889 us; speedup vs baseline: 1.1891x; 1.1891x over previous
//
#include <hip/hip_runtime.h>
#include <hip/hip_bf16.h>

#define Vv 32000
#define Tz 256
#define Hz 256
#define RING 128
#define BK 16
#define HST 264   // LDS h row stride in BYTES (fp8): 33 x 8B, odd slots -> low conflict

typedef __attribute__((ext_vector_type(8))) short short8;
typedef __attribute__((ext_vector_type(4))) float f32x4;

__device__ __forceinline__ float sigm(float x) { return 1.f / (1.f + __expf(-x)); }
__device__ __forceinline__ float tanh_(float x) {
    float e = __expf(2.f * x);
    return 1.f - 2.f / (e + 1.f);
}
__device__ __forceinline__ unsigned short f2bf(float x) {
    union { __hip_bfloat16 h; unsigned short u; } cv; cv.h = __float2bfloat16(x); return cv.u;
}
__device__ __forceinline__ float bf2f(unsigned short u) {
    union { unsigned u; float f; } cv; cv.u = ((unsigned)u) << 16; return cv.f;
}
__device__ __forceinline__ unsigned f2fp8(float x) {
    return ((unsigned)__builtin_amdgcn_cvt_pk_fp8_f32(x, x, 0, false)) & 0xffu;
}

// ---------- embedding gather -> xs_bf [T][B][256] bf16 (row = t*32+b)
__global__ __launch_bounds__(64) void k_embed(const int* __restrict__ inp,
    const float* __restrict__ emb, __hip_bfloat16* __restrict__ xs) {
    int row = blockIdx.x;
    int t = row >> 5, b = row & 31;
    const float* src = emb + (size_t)inp[b * Tz + t] * Hz;
    int tid = threadIdx.x;
    float4 v = *(const float4*)&src[tid * 4];
    __hip_bfloat16* dst = xs + (size_t)row * Hz + tid * 4;
    dst[0] = __float2bfloat16(v.x); dst[1] = __float2bfloat16(v.y);
    dst[2] = __float2bfloat16(v.z); dst[3] = __float2bfloat16(v.w);
}

// ---------- W [512 k][1024 zc] f32 -> gate-grouped: gi = hid*4+gate (zc = gate*256+hid).
// W1 k<256 -> W1xG bf16; W1 k>=256 -> W1hG fp8; W2 k<256 -> W2xG fp8; W2 k>=256 -> W2hG fp8
__global__ __launch_bounds__(256) void k_wt(const float* __restrict__ W1,
    const float* __restrict__ W2, unsigned short* __restrict__ W1xG,
    unsigned char* __restrict__ W1hG, unsigned char* __restrict__ W2xG,
    unsigned char* __restrict__ W2hG)
{
    __shared__ float tile[64][65];
    int bid = blockIdx.x;
    int layer = bid >> 7;
    int tl = bid & 127;
    int kt = tl & 7, zt = tl >> 3;
    int k0 = kt * 64, zc0 = zt * 64;
    int gate = zt >> 2, hid0 = (zt & 3) * 64;
    const float* W = layer ? W2 : W1;
    int tid = threadIdx.x;
#pragma unroll
    for (int p = 0; p < 16; ++p) {
        int lin = p * 256 + tid;
        int kk = lin >> 6, zz = lin & 63;
        tile[kk][zz] = W[(size_t)(k0 + kk) * 1024 + zc0 + zz];
    }
    __syncthreads();
    int kb = k0 & 255;
    if (!layer && k0 < 256) {
#pragma unroll
        for (int p = 0; p < 16; ++p) {
            int lin = p * 256 + tid;
            int zz = lin >> 6, kk = lin & 63;
            int gi = (hid0 + zz) * 4 + gate;
            W1xG[(size_t)gi * 256 + kb + kk] = f2bf(tile[kk][zz]);
        }
    } else {
        unsigned char* dst = layer ? ((k0 < 256) ? W2xG : W2hG) : W1hG;
#pragma unroll
        for (int p = 0; p < 4; ++p) {
            int lin = p * 256 + tid;
            int zz = lin >> 4, kg = lin & 15;
            int gi = (hid0 + zz) * 4 + gate;
            unsigned r = (unsigned)__builtin_amdgcn_cvt_pk_fp8_f32(
                tile[kg * 4 + 0][zz], tile[kg * 4 + 1][zz], 0, false);
            r = (unsigned)__builtin_amdgcn_cvt_pk_fp8_f32(
                tile[kg * 4 + 2][zz], tile[kg * 4 + 3][zz], (int)r, true);
            *(unsigned*)&dst[(size_t)gi * 256 + kb + kg * 4] = r;
        }
    }
}

// ---------- z1x precompute: XS[8192][256] @ W1xG^T (+b1) -> z1xG [8192][1024 gi] bf16
__global__ __launch_bounds__(256) void k_xw(const __hip_bfloat16* __restrict__ Abf,
    const unsigned short* __restrict__ Bg, const float* __restrict__ b1v,
    unsigned short* __restrict__ outG)
{
    __shared__ __align__(16) unsigned short As[128 * 64];
    __shared__ __align__(16) unsigned short Bs[128 * 64];
    int tid = threadIdx.x;
    size_t r0 = (size_t)blockIdx.x * 128;
    size_t c0 = (size_t)blockIdx.y * 128;
    int l = tid & 63, w = tid >> 6, lr = l & 15, lk = l >> 4;
    f32x4 acc[2][8];
#pragma unroll
    for (int m = 0; m < 2; ++m)
#pragma unroll
        for (int f = 0; f < 8; ++f) acc[m][f] = (f32x4){0.f, 0.f, 0.f, 0.f};
    const unsigned short* A = (const unsigned short*)Abf;
    for (int kt = 0; kt < 4; ++kt) {
#pragma unroll
        for (int i = 0; i < 4; ++i) {
            int fi = i * 256 + tid;
            int row = fi >> 3, seg = fi & 7;
            int dseg = seg ^ (row & 7);
            *(short8*)&As[row * 64 + dseg * 8] =
                *(const short8*)&A[(r0 + row) * 256 + kt * 64 + seg * 8];
            *(short8*)&Bs[row * 64 + dseg * 8] =
                *(const short8*)&Bg[((size_t)c0 + row) * 256 + kt * 64 + seg * 8];
        }
        __syncthreads();
#pragma unroll
        for (int ks = 0; ks < 2; ++ks) {
            short8 a[2];
#pragma unroll
            for (int m = 0; m < 2; ++m) {
                int row = w * 32 + m * 16 + lr;
                a[m] = *(const short8*)&As[row * 64 + ((ks * 4 + lk) ^ (row & 7)) * 8];
            }
#pragma unroll
            for (int f = 0; f < 8; ++f) {
                int row = f * 16 + lr;
                short8 bfr = *(const short8*)&Bs[row * 64 + ((ks * 4 + lk) ^ (row & 7)) * 8];
#pragma unroll
                for (int m = 0; m < 2; ++m)
                    acc[m][f] = __builtin_amdgcn_mfma_f32_16x16x32_bf16(a[m], bfr, acc[m][f], 0, 0, 0);
            }
        }
        __syncthreads();
    }
#pragma unroll
    for (int f = 0; f < 8; ++f) {
        int gi = (int)c0 + f * 16 + lr;
        float bb = b1v[(gi & 3) * 256 + (gi >> 2)];
#pragma unroll
        for (int m = 0; m < 2; ++m)
#pragma unroll
            for (int j = 0; j < 4; ++j)
                outG[(r0 + w * 32 + m * 16 + lk * 4 + j) * 1024 + gi] =
                    f2bf(acc[m][f][j] + bb);
    }
}

// ---------- persistent 3-stage LSTM pipeline with BATCHED release/acquire handoff.
// A(bid0): h1 recurrence. B(bid1): z2x = W2x·h1+b2. C(bid2): h2 recurrence.
// Per BK=16 steps: producer does plain stores, one __syncthreads (vmcnt drain),
// one RELEASE flag store (wbL2). Consumer: one ACQUIRE poll (invL1/L2), then plain loads.
// bid>=3: folded softmax_w transpose.
__global__ __launch_bounds__(512, 2) void k_lstm6(
    const unsigned short* __restrict__ z1xG,    // [8192][1024] bf16 (b1 folded in)
    const unsigned char*  __restrict__ W1hG,    // [1024][256] fp8
    const unsigned char*  __restrict__ W2xG,
    const unsigned char*  __restrict__ W2hG,
    const float* __restrict__ b2v,
    unsigned char*  __restrict__ h1hist,        // [256][32][256] fp8
    unsigned short* __restrict__ z2x,           // ring [RING][32][1024] bf16
    unsigned short* __restrict__ houtB,         // [8192][256] bf16 (row = b*256+t)
    unsigned* __restrict__ flags,               // fA=[0], fB=[16], fC=[32]
    const float* __restrict__ sw, __hip_bfloat16* __restrict__ swt)
{
    __shared__ __align__(16) unsigned char hl[2][32 * HST];
    __shared__ float tile[64][65];
    int bid = blockIdx.x, tid = threadIdx.x;

    if (bid >= 3) {        // folded softmax_w transpose (29 blocks)
        int idx = bid - 3;
        for (int tl = idx; tl < 2000; tl += 29) {
            int kt = tl & 3, vt = tl >> 2;
            int k0 = kt * 64, v0 = vt * 64;
#pragma unroll
            for (int pp = 0; pp < 8; ++pp) {
                int lin = pp * 512 + tid;
                int kk = lin >> 6, vv = lin & 63;
                tile[kk][vv] = sw[(size_t)(k0 + kk) * Vv + v0 + vv];
            }
            __syncthreads();
#pragma unroll
            for (int pp = 0; pp < 8; ++pp) {
                int lin = pp * 512 + tid;
                int vv = lin >> 6, kk = lin & 63;
                swt[(size_t)(v0 + vv) * 256 + k0 + kk] = __float2bfloat16(tile[kk][vv]);
            }
            __syncthreads();
        }
        return;
    }

    int role = bid;
    int w = tid >> 6, l = tid & 63, lr = l & 15, lk = l >> 4;
    const unsigned char* WG = (role == 0) ? W1hG : (role == 1) ? W2xG : W2hG;

    // weight fragments: 64 x 8B = 128 VGPR/lane
    long Wf[8][8];
#pragma unroll
    for (int hbl = 0; hbl < 8; ++hbl)
#pragma unroll
        for (int kc = 0; kc < 8; ++kc)
            Wf[hbl][kc] = *(const long*)&WG[(size_t)(((w * 8 + hbl) * 16 + lr) * 256 + kc * 32 + lk * 8)];

    for (int u = tid; u < 2 * 32 * HST / 4; u += 512) ((unsigned*)hl)[u] = 0u;  // h(-1)=0

    float c_[8][2];
#pragma unroll
    for (int i = 0; i < 8; ++i) { c_[i][0] = 0.f; c_[i][1] = 0.f; }
    f32x4 b2q[8];
    if (role == 1) {
#pragma unroll
        for (int hbl = 0; hbl < 8; ++hbl) {
            int hidl = (w * 8 + hbl) * 4 + lk;
#pragma unroll
            for (int j = 0; j < 4; ++j) b2q[hbl][j] = b2v[j * 256 + hidl];
        }
    }
    unsigned* fA = &flags[0]; unsigned* fB = &flags[16]; unsigned* fC = &flags[32];
    int ba = tid >> 4, sg = tid & 15;
    int cur = 0;
    __syncthreads();

    for (int T0 = 0; T0 < 256; T0 += BK) {
        // ---- batch-start waits
        if (role == 1) {
            if (tid == 0) {
                while (__hip_atomic_load(fA, __ATOMIC_ACQUIRE, __HIP_MEMORY_SCOPE_AGENT) < (unsigned)(T0 + BK))
                    __builtin_amdgcn_s_sleep(16);
                if (T0 >= RING)   // ring backpressure (never blocks in steady state)
                    while (__hip_atomic_load(fC, __ATOMIC_RELAXED, __HIP_MEMORY_SCOPE_AGENT) < (unsigned)(T0 - (RING - BK)))
                        __builtin_amdgcn_s_sleep(16);
            }
            __syncthreads();
            {   // stage h1(T0)
                uint4 g = *(const uint4*)&h1hist[(size_t)T0 * 8192 + ba * 256 + sg * 16];
                *(uint4*)&hl[cur][ba * HST + sg * 16] = g;
            }
            __syncthreads();
        } else if (role == 2) {
            if (tid == 0)
                while (__hip_atomic_load(fB, __ATOMIC_ACQUIRE, __HIP_MEMORY_SCOPE_AGENT) < (unsigned)(T0 + BK))
                    __builtin_amdgcn_s_sleep(16);
            __syncthreads();
        }

        for (int tt = 0; tt < BK; ++tt) {
            int t = T0 + tt;
            if (role == 0) {
                // ---- stage A: z = W1h·h1(t-1) + z1x(t)
                uint2 ad[8][2];
#pragma unroll
                for (int hbl = 0; hbl < 8; ++hbl)
#pragma unroll
                    for (int bh = 0; bh < 2; ++bh)
                        ad[hbl][bh] = *(const uint2*)&z1xG[((size_t)(t * 32 + bh * 16 + lr)) * 1024 + (w * 8 + hbl) * 16 + lk * 4];
                unsigned pkv[2][8];
#pragma unroll
                for (int bh = 0; bh < 2; ++bh) {
                    f32x4 acc[8];
#pragma unroll
                    for (int hbl = 0; hbl < 8; ++hbl) acc[hbl] = (f32x4){0.f, 0.f, 0.f, 0.f};
#pragma unroll
                    for (int kc = 0; kc < 8; ++kc) {
                        long hf = *(const long*)&hl[cur][(bh * 16 + lr) * HST + kc * 32 + lk * 8];
#pragma unroll
                        for (int hbl = 0; hbl < 8; ++hbl)
                            acc[hbl] = __builtin_amdgcn_mfma_f32_16x16x32_fp8_fp8(Wf[hbl][kc], hf, acc[hbl], 0, 0, 0);
                    }
#pragma unroll
                    for (int hbl = 0; hbl < 8; ++hbl) {
                        float zi = acc[hbl][0] + bf2f((unsigned short)(ad[hbl][bh].x & 0xffff));
                        float zj = acc[hbl][1] + bf2f((unsigned short)(ad[hbl][bh].x >> 16));
                        float zf = acc[hbl][2] + bf2f((unsigned short)(ad[hbl][bh].y & 0xffff));
                        float zo = acc[hbl][3] + bf2f((unsigned short)(ad[hbl][bh].y >> 16));
                        float cn = c_[hbl][bh] * sigm(zf + 1.f) + sigm(zi) * tanh_(zj);
                        c_[hbl][bh] = cn;
                        float hv = tanh_(cn) * sigm(zo);
                        unsigned x = f2fp8(hv) << (lk * 8);
                        x |= __shfl_xor(x, 16); x |= __shfl_xor(x, 32);
                        pkv[bh][hbl] = x;
                    }
                }
                // write h1(t) into hl[cur^1] + publish plain to h1hist
                if (lk == 0) {
#pragma unroll
                    for (int bh = 0; bh < 2; ++bh)
#pragma unroll
                        for (int hbl = 0; hbl < 8; ++hbl) {
                            int br = bh * 16 + lr, hb = (w * 8 + hbl) * 4;
                            *(unsigned*)&hl[cur ^ 1][br * HST + hb] = pkv[bh][hbl];
                            *(unsigned*)&h1hist[(size_t)t * 8192 + br * 256 + hb] = pkv[bh][hbl];
                        }
                }
                __syncthreads();   // hl[cur^1] visible + all waves' stores drained
                cur ^= 1;
            } else if (role == 1) {
                // ---- stage B: z2x(t) = W2x·h1(t) + b2 -> ring (plain stores)
                uint4 pre;
                bool hasp = (tt + 1 < BK);
                if (hasp)
                    pre = *(const uint4*)&h1hist[(size_t)(t + 1) * 8192 + ba * 256 + sg * 16];
                int ts = t & (RING - 1);
#pragma unroll
                for (int bh = 0; bh < 2; ++bh) {
                    f32x4 acc[8];
#pragma unroll
                    for (int hbl = 0; hbl < 8; ++hbl) acc[hbl] = (f32x4){0.f, 0.f, 0.f, 0.f};
#pragma unroll
                    for (int kc = 0; kc < 8; ++kc) {
                        long hf = *(const long*)&hl[cur][(bh * 16 + lr) * HST + kc * 32 + lk * 8];
#pragma unroll
                        for (int hbl = 0; hbl < 8; ++hbl)
                            acc[hbl] = __builtin_amdgcn_mfma_f32_16x16x32_fp8_fp8(Wf[hbl][kc], hf, acc[hbl], 0, 0, 0);
                    }
#pragma unroll
                    for (int hbl = 0; hbl < 8; ++hbl) {
                        f32x4 z = acc[hbl] + b2q[hbl];
                        unsigned lo = (unsigned)f2bf(z[0]) | ((unsigned)f2bf(z[1]) << 16);
                        unsigned hi = (unsigned)f2bf(z[2]) | ((unsigned)f2bf(z[3]) << 16);
                        unsigned long long v = (unsigned long long)lo | ((unsigned long long)hi << 32);
                        *(unsigned long long*)&z2x[((size_t)ts * 32 + bh * 16 + lr) * 1024 + (w * 8 + hbl) * 16 + lk * 4] = v;
                    }
                }
                if (hasp) *(uint4*)&hl[cur ^ 1][ba * HST + sg * 16] = pre;
                __syncthreads();
                if (hasp) cur ^= 1;
            } else {
                // ---- stage C: z = W2h·h2(t-1) + z2x(t)
                int ts = t & (RING - 1);
                unsigned long long ad[8][2];
#pragma unroll
                for (int hbl = 0; hbl < 8; ++hbl)
#pragma unroll
                    for (int bh = 0; bh < 2; ++bh)
                        ad[hbl][bh] = *(const unsigned long long*)&z2x[((size_t)ts * 32 + bh * 16 + lr) * 1024 + (w * 8 + hbl) * 16 + lk * 4];
                unsigned pkv[2][8], pbf[2][8];
#pragma unroll
                for (int bh = 0; bh < 2; ++bh) {
                    f32x4 acc[8];
#pragma unroll
                    for (int hbl = 0; hbl < 8; ++hbl) acc[hbl] = (f32x4){0.f, 0.f, 0.f, 0.f};
#pragma unroll
                    for (int kc = 0; kc < 8; ++kc) {
                        long hf = *(const long*)&hl[cur][(bh * 16 + lr) * HST + kc * 32 + lk * 8];
#pragma unroll
                        for (int hbl = 0; hbl < 8; ++hbl)
                            acc[hbl] = __builtin_amdgcn_mfma_f32_16x16x32_fp8_fp8(Wf[hbl][kc], hf, acc[hbl], 0, 0, 0);
                    }
#pragma unroll
                    for (int hbl = 0; hbl < 8; ++hbl) {
                        unsigned adx = (unsigned)(ad[hbl][bh] & 0xffffffffu);
                        unsigned ady = (unsigned)(ad[hbl][bh] >> 32);
                        float zi = acc[hbl][0] + bf2f((unsigned short)(adx & 0xffff));
                        float zj = acc[hbl][1] + bf2f((unsigned short)(adx >> 16));
                        float zf = acc[hbl][2] + bf2f((unsigned short)(ady & 0xffff));
                        float zo = acc[hbl][3] + bf2f((unsigned short)(ady >> 16));
                        float cn = c_[hbl][bh] * sigm(zf + 1.f) + sigm(zi) * tanh_(zj);
                        c_[hbl][bh] = cn;
                        float hv = tanh_(cn) * sigm(zo);
                        unsigned x = f2fp8(hv) << (lk * 8);
                        x |= __shfl_xor(x, 16); x |= __shfl_xor(x, 32);
                        pkv[bh][hbl] = x;
                        unsigned y = ((unsigned)f2bf(hv)) << ((lk & 1) * 16);
                        y |= __shfl_xor(y, 16);
                        pbf[bh][hbl] = y;
                    }
                }
#pragma unroll
                for (int bh = 0; bh < 2; ++bh)
#pragma unroll
                    for (int hbl = 0; hbl < 8; ++hbl) {
                        int br = bh * 16 + lr, hb = (w * 8 + hbl) * 4;
                        if (lk == 0) *(unsigned*)&hl[cur ^ 1][br * HST + hb] = pkv[bh][hbl];
                        if ((lk & 1) == 0)
                            *(unsigned*)&houtB[((size_t)(br * 256 + t)) * 256 + hb + lk] = pbf[bh][hbl];
                    }
                __syncthreads();
                cur ^= 1;
            }
        }

        // ---- batch-end flags (preceded by final step's __syncthreads -> vmcnt drained)
        if (tid == 0) {
            if (role == 0)
                __hip_atomic_store(fA, (unsigned)(T0 + BK), __ATOMIC_RELEASE, __HIP_MEMORY_SCOPE_AGENT);
            else if (role == 1)
                __hip_atomic_store(fB, (unsigned)(T0 + BK), __ATOMIC_RELEASE, __HIP_MEMORY_SCOPE_AGENT);
            else
                __hip_atomic_store(fC, (unsigned)(T0 + BK), __ATOMIC_RELAXED, __HIP_MEMORY_SCOPE_AGENT);
        }
    }
}

// ---------- logits GEMM: 128x128 tile, BK=64, XOR-swizzled LDS, streaming sum-of-exp
__global__ __launch_bounds__(256) void k_gemm(const __hip_bfloat16* __restrict__ Abf,
    const __hip_bfloat16* __restrict__ Bbf, const float* __restrict__ sb,
    float* __restrict__ row_sum)
{
    __shared__ __align__(16) unsigned short As[128 * 64];
    __shared__ __align__(16) unsigned short Bs[128 * 64];
    int tid = threadIdx.x;
    size_t r0 = (size_t)blockIdx.x * 128;
    size_t c0 = (size_t)blockIdx.y * 128;
    int l = tid & 63, w = tid >> 6, lr = l & 15, lk = l >> 4;

    f32x4 acc[2][8];
#pragma unroll
    for (int m = 0; m < 2; ++m)
#pragma unroll
        for (int f = 0; f < 8; ++f) acc[m][f] = (f32x4){0.f, 0.f, 0.f, 0.f};

    const unsigned short* A = (const unsigned short*)Abf;
    const unsigned short* B = (const unsigned short*)Bbf;

    for (int kt = 0; kt < 4; ++kt) {
#pragma unroll
        for (int i = 0; i < 4; ++i) {
            int fi = i * 256 + tid;
            int row = fi >> 3, seg = fi & 7;
            int dseg = seg ^ (row & 7);
            *(short8*)&As[row * 64 + dseg * 8] =
                *(const short8*)&A[(r0 + row) * 256 + kt * 64 + seg * 8];
            *(short8*)&Bs[row * 64 + dseg * 8] =
                *(const short8*)&B[(c0 + row) * 256 + kt * 64 + seg * 8];
        }
        __syncthreads();
#pragma unroll
        for (int ks = 0; ks < 2; ++ks) {
            short8 a[2];
#pragma unroll
            for (int m = 0; m < 2; ++m) {
                int row = w * 32 + m * 16 + lr;
                a[m] = *(const short8*)&As[row * 64 + ((ks * 4 + lk) ^ (row & 7)) * 8];
            }
#pragma unroll
            for (int f = 0; f < 8; ++f) {
                int row = f * 16 + lr;
                short8 bfr = *(const short8*)&Bs[row * 64 + ((ks * 4 + lk) ^ (row & 7)) * 8];
#pragma unroll
                for (int m = 0; m < 2; ++m)
                    acc[m][f] = __builtin_amdgcn_mfma_f32_16x16x32_bf16(a[m], bfr, acc[m][f], 0, 0, 0);
            }
        }
        __syncthreads();
    }

    float sums[2][4] = {{0.f,0.f,0.f,0.f},{0.f,0.f,0.f,0.f}};
#pragma unroll
    for (int f = 0; f < 8; ++f) {
        float sbv = sb[c0 + f * 16 + lr];
#pragma unroll
        for (int m = 0; m < 2; ++m)
#pragma unroll
            for (int j = 0; j < 4; ++j) sums[m][j] += __expf(acc[m][f][j] + sbv);
    }
#pragma unroll
    for (int msk = 1; msk <= 8; msk <<= 1)
#pragma unroll
        for (int m = 0; m < 2; ++m)
#pragma unroll
            for (int j = 0; j < 4; ++j) sums[m][j] += __shfl_xor(sums[m][j], msk);
    if (lr == 0) {
#pragma unroll
        for (int m = 0; m < 2; ++m)
#pragma unroll
            for (int j = 0; j < 4; ++j)
                atomicAdd(&row_sum[r0 + w * 32 + m * 16 + lk * 4 + j], sums[m][j]);
    }
}

// ---------- per-row loss: log(sum_exp) - target logit
__global__ __launch_bounds__(256) void k_loss(const __hip_bfloat16* __restrict__ houtB,
    const __hip_bfloat16* __restrict__ swt, const float* __restrict__ sb,
    const int* __restrict__ tgts, const float* __restrict__ row_sum,
    float* __restrict__ out)
{
    int r = blockIdx.x * 256 + threadIdx.x;
    int tg = tgts[r];
    const unsigned short* h = (const unsigned short*)houtB + (size_t)r * Hz;
    const unsigned short* wp = (const unsigned short*)swt + (size_t)tg * Hz;
    float acc = 0.f;
#pragma unroll 4
    for (int k8 = 0; k8 < 32; ++k8) {
        short8 hv = *(const short8*)&h[k8 * 8];
        short8 wv = *(const short8*)&wp[k8 * 8];
#pragma unroll
        for (int e = 0; e < 8; ++e)
            acc += bf2f((unsigned short)hv[e]) * bf2f((unsigned short)wv[e]);
    }
    float loss = logf(row_sum[r]) - (acc + sb[tg]);
#pragma unroll
    for (int m = 1; m < 64; m <<= 1) loss += __shfl_xor(loss, m);
    __shared__ float red[4];
    int l = threadIdx.x & 63, wvv = threadIdx.x >> 6;
    if (l == 0) red[wvv] = loss;
    __syncthreads();
    if (threadIdx.x == 0) {
        float s = red[0] + red[1] + red[2] + red[3];
        atomicAdd(out, s * (1.f / 8192.f));
    }
}

extern "C" void kernel_launch(void* const* d_in, const int* in_sizes, int n_in,
                              void* d_out, int out_size, void* d_ws, size_t ws_size,
                              hipStream_t stream)
{
    const int*   inp = (const int*)d_in[0];
    const int*   tgt = (const int*)d_in[1];
    const float* emb = (const float*)d_in[2];
    const float* W1  = (const float*)d_in[3];
    const float* b1  = (const float*)d_in[4];
    const float* W2  = (const float*)d_in[5];
    const float* b2  = (const float*)d_in[6];
    const float* sw  = (const float*)d_in[7];
    const float* sb  = (const float*)d_in[8];
    float* out = (float*)d_out;

    char* ws = (char*)d_ws;
    size_t off = 0;
    __hip_bfloat16* SWT  = (__hip_bfloat16*)(ws + off); off += (size_t)Vv * Hz * 2;        // 16,384,000
    // union: {XS + W1xG} (dead after k_xw)  aliased with  Z2X ring (alive in k_lstm6 only)
    size_t uni = off;                                   off += (size_t)RING * 32 * 1024 * 2; // 8,388,608
    __hip_bfloat16* XS   = (__hip_bfloat16*)(ws + uni);                 // 4,194,304
    unsigned short* W1xG = (unsigned short*)(ws + uni + 4194304);       //   524,288
    unsigned short* Z2X  = (unsigned short*)(ws + uni);
    unsigned char*  W1hG = (unsigned char*)(ws + off);  off += (size_t)1024 * 256;         //    262,144
    unsigned char*  W2xG = (unsigned char*)(ws + off);  off += (size_t)1024 * 256;         //    262,144
    unsigned char*  W2hG = (unsigned char*)(ws + off);  off += (size_t)1024 * 256;         //    262,144
    unsigned short* Z1xG = (unsigned short*)(ws + off); off += (size_t)8192 * 1024 * 2;    // 16,777,216
    unsigned char*  H1h  = (unsigned char*)(ws + off);  off += (size_t)Tz * 8192;          //  2,097,152
    unsigned short* HoutB= (unsigned short*)(ws + off); off += (size_t)8192 * Hz * 2;      //  4,194,304
    float* row_sum       = (float*)(ws + off);          off += 8192 * 4;                   //     32,768
    unsigned* flags      = (unsigned*)(ws + off);       off += 64 * 4;                     //        256
    // total ~46.4 MiB

    hipMemsetAsync(row_sum, 0, 8192 * 4 + 64 * 4, stream);   // row_sum + flags
    hipMemsetAsync(out, 0, sizeof(float), stream);

    k_embed<<<8192, 64, 0, stream>>>(inp, emb, XS);
    k_wt<<<256, 256, 0, stream>>>(W1, W2, W1xG, W1hG, W2xG, W2hG);
    k_xw<<<dim3(64, 8), 256, 0, stream>>>(XS, W1xG, b1, Z1xG);
    k_lstm6<<<32, 512, 0, stream>>>(Z1xG, W1hG, W2xG, W2hG, b2,
                                    H1h, Z2X, (unsigned short*)HoutB, flags, sw, SWT);
    k_gemm<<<dim3(64, 250), 256, 0, stream>>>((const __hip_bfloat16*)HoutB, SWT, sb, row_sum);
    k_loss<<<32, 256, 0, stream>>>((const __hip_bfloat16*)HoutB, SWT, sb, tgt, row_sum, out);
}

// Round 9
// 2422.073 us; speedup vs baseline: 1.9892x; 1.6729x over previous
//
#include <hip/hip_runtime.h>
#include <hip/hip_bf16.h>

#define Vv 32000
#define Tz 256
#define Hz 256
#define XSTR 520   // xh row stride in BYTES (fp8 k=512 + 8 pad)

typedef __attribute__((ext_vector_type(8))) short short8;
typedef __attribute__((ext_vector_type(4))) float f32x4;

__device__ __forceinline__ float sigm(float x) { return 1.f / (1.f + __expf(-x)); }
__device__ __forceinline__ float tanh_(float x) {
    float e = __expf(2.f * x);
    return 1.f - 2.f / (e + 1.f);
}
__device__ __forceinline__ unsigned short f2bf(float x) {
    union { __hip_bfloat16 h; unsigned short u; } cv; cv.h = __float2bfloat16(x); return cv.u;
}
__device__ __forceinline__ float bf2f(unsigned short u) {
    union { unsigned u; float f; } cv; cv.u = ((unsigned)u) << 16; return cv.f;
}
__device__ __forceinline__ unsigned f2fp8(float x) {
    return ((unsigned)__builtin_amdgcn_cvt_pk_fp8_f32(x, x, 0, false)) & 0xffu;
}

// ---------- embedding gather -> xs fp8 [256 t][32 b][256]
__global__ __launch_bounds__(64) void k_embed(const int* __restrict__ inp,
    const float* __restrict__ emb, unsigned char* __restrict__ xs) {
    int row = blockIdx.x;              // t*32 + b
    int t = row >> 5, b = row & 31;
    const float* src = emb + (size_t)inp[b * Tz + t] * Hz;
    int tid = threadIdx.x;
    float4 v = *(const float4*)&src[tid * 4];
    unsigned r = (unsigned)__builtin_amdgcn_cvt_pk_fp8_f32(v.x, v.y, 0, false);
    r = (unsigned)__builtin_amdgcn_cvt_pk_fp8_f32(v.z, v.w, (int)r, true);
    *(unsigned*)&xs[(size_t)row * 256 + tid * 4] = r;
}

// ---------- W [512 k][1024 zc] f32 -> WG fp8 [layer][o][512 gi][512 k]
// zc = gate*256 + o*128 + hidl;  gi = hidl*4 + gate;  k passthrough (x-half then h-half).
__global__ __launch_bounds__(256) void k_wt(const float* __restrict__ W1,
    const float* __restrict__ W2, unsigned char* __restrict__ WG)
{
    __shared__ float tile[64][65];
    int bid = blockIdx.x;              // 2 layers x 8 ktiles x 16 zctiles
    int layer = bid >> 7;
    int tl = bid & 127;
    int kt = tl & 7, zt = tl >> 3;
    int k0 = kt * 64, zc0 = zt * 64;
    int gate = zc0 >> 8, o = (zc0 >> 7) & 1, hid0 = zc0 & 127;  // hid0 in {0,64}
    const float* W = layer ? W2 : W1;
    int tid = threadIdx.x;
#pragma unroll
    for (int p = 0; p < 16; ++p) {
        int lin = p * 256 + tid;
        int kk = lin >> 6, zz = lin & 63;
        tile[kk][zz] = W[(size_t)(k0 + kk) * 1024 + zc0 + zz];
    }
    __syncthreads();
    unsigned char* dst = WG + ((size_t)(layer * 2 + o) * 512) * 512;
#pragma unroll
    for (int p = 0; p < 4; ++p) {
        int lin = p * 256 + tid;
        int zz = lin >> 4, kg = lin & 15;
        int gi = (hid0 + zz) * 4 + gate;
        unsigned r = (unsigned)__builtin_amdgcn_cvt_pk_fp8_f32(
            tile[kg * 4 + 0][zz], tile[kg * 4 + 1][zz], 0, false);
        r = (unsigned)__builtin_amdgcn_cvt_pk_fp8_f32(
            tile[kg * 4 + 2][zz], tile[kg * 4 + 3][zz], (int)r, true);
        *(unsigned*)&dst[(size_t)gi * 512 + k0 + kg * 4] = r;
    }
}

// ---------- persistent LSTM: 4 working blocks. bid = layer*2 + o; block owns
// hid-half o of its layer with FULL K=512 fp8 weights in VGPRs (128/lane).
// Per step: tiny h exchange only. Pairwise partner flag + forward A->C flags.
// bid>=4: folded softmax_w transpose with NON-TEMPORAL accesses (keeps L2 clean
// so the per-step release wbL2 stays ~free).
__global__ __launch_bounds__(512, 2) void k_lstm7(
    const unsigned char* __restrict__ xs,       // [256][32][256] fp8
    const unsigned char* __restrict__ WG,       // [2][2][512][512] fp8
    const float* __restrict__ b1v, const float* __restrict__ b2v,
    unsigned char* __restrict__ h1hist,         // [256][32][256] fp8 (full history)
    unsigned char* __restrict__ h2pub,          // [2][32][256] fp8 (slot = t&1)
    unsigned short* __restrict__ houtB,         // [8192][256] bf16 (row = b*256+t)
    unsigned* __restrict__ flags,               // fA0[0] fA1[16] fC0[32] fC1[48]
    const float* __restrict__ sw, __hip_bfloat16* __restrict__ swt)
{
    __shared__ __align__(16) unsigned char xh[2][32 * XSTR];
    __shared__ float tile[64][65];
    int bid = blockIdx.x, tid = threadIdx.x;

    if (bid >= 4) {        // softmax_w transpose, 28 workers, nt loads/stores
        int idx = bid - 4;
        for (int tl = idx; tl < 2000; tl += 28) {
            int kt = tl & 3, vt = tl >> 2;
            int k0 = kt * 64, v0 = vt * 64;
#pragma unroll
            for (int pp = 0; pp < 8; ++pp) {
                int lin = pp * 512 + tid;
                int kk = lin >> 6, vv = lin & 63;
                tile[kk][vv] = __builtin_nontemporal_load(&sw[(size_t)(k0 + kk) * Vv + v0 + vv]);
            }
            __syncthreads();
#pragma unroll
            for (int pp = 0; pp < 8; ++pp) {
                int lin = pp * 512 + tid;
                int vv = lin >> 6, kk = lin & 63;
                __builtin_nontemporal_store(f2bf(tile[kk][vv]),
                    (unsigned short*)&swt[(size_t)(v0 + vv) * 256 + k0 + kk]);
            }
            __syncthreads();
        }
        return;
    }

    int layer = bid >> 1, o = bid & 1;
    int w = tid >> 6, l = tid & 63, lr = l & 15, lk = l >> 4;

    // ---- weights -> VGPRs: 4 hbl x 16 kc x 8B = 128 VGPR/lane
    const unsigned char* Wp = WG + ((size_t)(layer * 2 + o) * 512) * 512;
    long Wf[4][16];
#pragma unroll
    for (int hbl = 0; hbl < 4; ++hbl)
#pragma unroll
        for (int kc = 0; kc < 16; ++kc)
            Wf[hbl][kc] = *(const long*)&Wp[(size_t)((w * 4 + hbl) * 16 + lr) * 512 + kc * 32 + lk * 8];

    const float* bv = layer ? b2v : b1v;
    f32x4 bq[4];
#pragma unroll
    for (int hbl = 0; hbl < 4; ++hbl)
#pragma unroll
        for (int j = 0; j < 4; ++j)
            bq[hbl][j] = bv[j * 256 + o * 128 + (w * 4 + hbl) * 4 + lk];
    float c_[4][2];
#pragma unroll
    for (int i = 0; i < 4; ++i) { c_[i][0] = 0.f; c_[i][1] = 0.f; }

    unsigned* fA0 = &flags[0];  unsigned* fA1 = &flags[16];
    unsigned* fC0 = &flags[32]; unsigned* fC1 = &flags[48];
    unsigned* myf = layer ? (o ? fC1 : fC0) : (o ? fA1 : fA0);
    unsigned* pf  = layer ? (o ? fC0 : fC1) : (o ? fA0 : fA1);

    // zero both LDS buffers (h(-1)=0), then layer1 stages xs(0)
    for (int u = tid; u < 2 * 32 * XSTR / 4; u += 512) ((unsigned*)xh)[u] = 0u;
    __syncthreads();
    int cb = tid >> 4, cs = tid & 15;
    if (!layer)
        *(uint4*)&xh[0][cb * XSTR + cs * 16] = *(const uint4*)&xs[(size_t)cb * 256 + cs * 16];
    __syncthreads();

    for (int t = 0; t < 256; ++t) {
        int cur = t & 1;
        if (!layer) {
            // prefetch xs(t+1) into buf[cur^1] x-part (static data, safe anytime)
            if (t < 255) {
                uint4 pv = *(const uint4*)&xs[(size_t)(t + 1) * 8192 + cb * 256 + cs * 16];
                *(uint4*)&xh[cur ^ 1][cb * XSTR + cs * 16] = pv;
            }
        } else {
            // stage h1(t): poll both A flags (relaxed), one acquire, plain 8KB read
            if (tid == 0) {
                unsigned t1 = (unsigned)(t + 1);
                while (__hip_atomic_load(fA0, __ATOMIC_RELAXED, __HIP_MEMORY_SCOPE_AGENT) < t1)
                    __builtin_amdgcn_s_sleep(1);
                while (__hip_atomic_load(fA1, __ATOMIC_RELAXED, __HIP_MEMORY_SCOPE_AGENT) < t1)
                    __builtin_amdgcn_s_sleep(1);
                (void)__hip_atomic_load(fA0, __ATOMIC_ACQUIRE, __HIP_MEMORY_SCOPE_AGENT);
            }
            __syncthreads();
            uint4 g = *(const uint4*)&h1hist[(size_t)t * 8192 + cb * 256 + cs * 16];
            *(uint4*)&xh[cur][cb * XSTR + cs * 16] = g;
            __syncthreads();
        }

        // ---- MFMA K=512: acc[hbl][bh], D row = gi-local (lk*4+j), col = batch (lr)
        f32x4 acc[4][2];
#pragma unroll
        for (int hbl = 0; hbl < 4; ++hbl)
#pragma unroll
            for (int bh = 0; bh < 2; ++bh) acc[hbl][bh] = (f32x4){0.f, 0.f, 0.f, 0.f};
#pragma unroll
        for (int kc = 0; kc < 16; ++kc) {
            long h0 = *(const long*)&xh[cur][lr * XSTR + kc * 32 + lk * 8];
            long h1 = *(const long*)&xh[cur][(16 + lr) * XSTR + kc * 32 + lk * 8];
#pragma unroll
            for (int hbl = 0; hbl < 4; ++hbl) {
                acc[hbl][0] = __builtin_amdgcn_mfma_f32_16x16x32_fp8_fp8(Wf[hbl][kc], h0, acc[hbl][0], 0, 0, 0);
                acc[hbl][1] = __builtin_amdgcn_mfma_f32_16x16x32_fp8_fp8(Wf[hbl][kc], h1, acc[hbl][1], 0, 0, 0);
            }
        }

        // ---- gates in registers; pack h (fp8 quad + bf16 pair)
        unsigned pk8[2][4], pbf[2][4];
#pragma unroll
        for (int bh = 0; bh < 2; ++bh)
#pragma unroll
            for (int hbl = 0; hbl < 4; ++hbl) {
                float zi = acc[hbl][bh][0] + bq[hbl][0];
                float zj = acc[hbl][bh][1] + bq[hbl][1];
                float zf = acc[hbl][bh][2] + bq[hbl][2];
                float zo = acc[hbl][bh][3] + bq[hbl][3];
                float cn = c_[hbl][bh] * sigm(zf + 1.f) + sigm(zi) * tanh_(zj);
                c_[hbl][bh] = cn;
                float hv = tanh_(cn) * sigm(zo);
                unsigned x = f2fp8(hv) << (lk * 8);
                x |= __shfl_xor(x, 16); x |= __shfl_xor(x, 32);
                pk8[bh][hbl] = x;
                if (layer) {
                    unsigned y = ((unsigned)f2bf(hv)) << ((lk & 1) * 16);
                    y |= __shfl_xor(y, 16);
                    pbf[bh][hbl] = y;
                }
            }

        // ---- own-half: LDS next-buf h-part + global publish
#pragma unroll
        for (int bh = 0; bh < 2; ++bh)
#pragma unroll
            for (int hbl = 0; hbl < 4; ++hbl) {
                int br = bh * 16 + lr;
                int hb = o * 128 + (w * 4 + hbl) * 4;
                if (lk == 0) {
                    *(unsigned*)&xh[cur ^ 1][br * XSTR + 256 + hb] = pk8[bh][hbl];
                    if (!layer)
                        *(unsigned*)&h1hist[(size_t)t * 8192 + br * 256 + hb] = pk8[bh][hbl];
                    else
                        *(unsigned*)&h2pub[(size_t)(t & 1) * 8192 + br * 256 + hb] = pk8[bh][hbl];
                }
                if (layer && (lk & 1) == 0)
                    __builtin_nontemporal_store(pbf[bh][hbl],
                        (unsigned*)&houtB[((size_t)(br * 256 + t)) * 256 + hb + lk]);
            }
        __syncthreads();   // drains vmcnt: publishes committed
        if (tid == 0) {
            __hip_atomic_store(myf, (unsigned)(t + 1), __ATOMIC_RELEASE, __HIP_MEMORY_SCOPE_AGENT);
            while (__hip_atomic_load(pf, __ATOMIC_RELAXED, __HIP_MEMORY_SCOPE_AGENT) < (unsigned)(t + 1))
                __builtin_amdgcn_s_sleep(1);
            (void)__hip_atomic_load(pf, __ATOMIC_ACQUIRE, __HIP_MEMORY_SCOPE_AGENT);
        }
        __syncthreads();
        // ---- read partner h-half (4 KB) into buf[cur^1]
        if (tid < 256) {
            int b = tid >> 3, sg = tid & 7;
            int po = 1 - o;
            uint4 v;
            if (!layer) v = *(const uint4*)&h1hist[(size_t)t * 8192 + b * 256 + po * 128 + sg * 16];
            else        v = *(const uint4*)&h2pub[(size_t)(t & 1) * 8192 + b * 256 + po * 128 + sg * 16];
            *(uint4*)&xh[cur ^ 1][b * XSTR + 256 + po * 128 + sg * 16] = v;
        }
        __syncthreads();   // buf[cur^1] complete for step t+1
    }
}

// ---------- logits GEMM: 128x128 tile, BK=64, XOR-swizzled LDS, streaming sum-of-exp
__global__ __launch_bounds__(256) void k_gemm(const __hip_bfloat16* __restrict__ Abf,
    const __hip_bfloat16* __restrict__ Bbf, const float* __restrict__ sb,
    float* __restrict__ row_sum)
{
    __shared__ __align__(16) unsigned short As[128 * 64];
    __shared__ __align__(16) unsigned short Bs[128 * 64];
    int tid = threadIdx.x;
    size_t r0 = (size_t)blockIdx.x * 128;
    size_t c0 = (size_t)blockIdx.y * 128;
    int l = tid & 63, w = tid >> 6, lr = l & 15, lk = l >> 4;

    f32x4 acc[2][8];
#pragma unroll
    for (int m = 0; m < 2; ++m)
#pragma unroll
        for (int f = 0; f < 8; ++f) acc[m][f] = (f32x4){0.f, 0.f, 0.f, 0.f};

    const unsigned short* A = (const unsigned short*)Abf;
    const unsigned short* B = (const unsigned short*)Bbf;

    for (int kt = 0; kt < 4; ++kt) {
#pragma unroll
        for (int i = 0; i < 4; ++i) {
            int fi = i * 256 + tid;
            int row = fi >> 3, seg = fi & 7;
            int dseg = seg ^ (row & 7);
            *(short8*)&As[row * 64 + dseg * 8] =
                *(const short8*)&A[(r0 + row) * 256 + kt * 64 + seg * 8];
            *(short8*)&Bs[row * 64 + dseg * 8] =
                *(const short8*)&B[(c0 + row) * 256 + kt * 64 + seg * 8];
        }
        __syncthreads();
#pragma unroll
        for (int ks = 0; ks < 2; ++ks) {
            short8 a[2];
#pragma unroll
            for (int m = 0; m < 2; ++m) {
                int row = w * 32 + m * 16 + lr;
                a[m] = *(const short8*)&As[row * 64 + ((ks * 4 + lk) ^ (row & 7)) * 8];
            }
#pragma unroll
            for (int f = 0; f < 8; ++f) {
                int row = f * 16 + lr;
                short8 bfr = *(const short8*)&Bs[row * 64 + ((ks * 4 + lk) ^ (row & 7)) * 8];
#pragma unroll
                for (int m = 0; m < 2; ++m)
                    acc[m][f] = __builtin_amdgcn_mfma_f32_16x16x32_bf16(a[m], bfr, acc[m][f], 0, 0, 0);
            }
        }
        __syncthreads();
    }

    float sums[2][4] = {{0.f,0.f,0.f,0.f},{0.f,0.f,0.f,0.f}};
#pragma unroll
    for (int f = 0; f < 8; ++f) {
        float sbv = sb[c0 + f * 16 + lr];
#pragma unroll
        for (int m = 0; m < 2; ++m)
#pragma unroll
            for (int j = 0; j < 4; ++j) sums[m][j] += __expf(acc[m][f][j] + sbv);
    }
#pragma unroll
    for (int msk = 1; msk <= 8; msk <<= 1)
#pragma unroll
        for (int m = 0; m < 2; ++m)
#pragma unroll
            for (int j = 0; j < 4; ++j) sums[m][j] += __shfl_xor(sums[m][j], msk);
    if (lr == 0) {
#pragma unroll
        for (int m = 0; m < 2; ++m)
#pragma unroll
            for (int j = 0; j < 4; ++j)
                atomicAdd(&row_sum[r0 + w * 32 + m * 16 + lk * 4 + j], sums[m][j]);
    }
}

// ---------- per-row loss: log(sum_exp) - target logit
__global__ __launch_bounds__(256) void k_loss(const __hip_bfloat16* __restrict__ houtB,
    const __hip_bfloat16* __restrict__ swt, const float* __restrict__ sb,
    const int* __restrict__ tgts, const float* __restrict__ row_sum,
    float* __restrict__ out)
{
    int r = blockIdx.x * 256 + threadIdx.x;
    int tg = tgts[r];
    const unsigned short* h = (const unsigned short*)houtB + (size_t)r * Hz;
    const unsigned short* wp = (const unsigned short*)swt + (size_t)tg * Hz;
    float acc = 0.f;
#pragma unroll 4
    for (int k8 = 0; k8 < 32; ++k8) {
        short8 hv = *(const short8*)&h[k8 * 8];
        short8 wv = *(const short8*)&wp[k8 * 8];
#pragma unroll
        for (int e = 0; e < 8; ++e)
            acc += bf2f((unsigned short)hv[e]) * bf2f((unsigned short)wv[e]);
    }
    float loss = logf(row_sum[r]) - (acc + sb[tg]);
#pragma unroll
    for (int m = 1; m < 64; m <<= 1) loss += __shfl_xor(loss, m);
    __shared__ float red[4];
    int l = threadIdx.x & 63, wvv = threadIdx.x >> 6;
    if (l == 0) red[wvv] = loss;
    __syncthreads();
    if (threadIdx.x == 0) {
        float s = red[0] + red[1] + red[2] + red[3];
        atomicAdd(out, s * (1.f / 8192.f));
    }
}

extern "C" void kernel_launch(void* const* d_in, const int* in_sizes, int n_in,
                              void* d_out, int out_size, void* d_ws, size_t ws_size,
                              hipStream_t stream)
{
    const int*   inp = (const int*)d_in[0];
    const int*   tgt = (const int*)d_in[1];
    const float* emb = (const float*)d_in[2];
    const float* W1  = (const float*)d_in[3];
    const float* b1  = (const float*)d_in[4];
    const float* W2  = (const float*)d_in[5];
    const float* b2  = (const float*)d_in[6];
    const float* sw  = (const float*)d_in[7];
    const float* sb  = (const float*)d_in[8];
    float* out = (float*)d_out;

    char* ws = (char*)d_ws;
    size_t off = 0;
    __hip_bfloat16* SWT  = (__hip_bfloat16*)(ws + off); off += (size_t)Vv * Hz * 2;       // 16,384,000
    unsigned char*  XS   = (unsigned char*)(ws + off);  off += (size_t)Tz * 32 * Hz;      //  2,097,152
    unsigned char*  WGb  = (unsigned char*)(ws + off);  off += (size_t)2 * 2 * 512 * 512; //  1,048,576
    unsigned char*  H1h  = (unsigned char*)(ws + off);  off += (size_t)Tz * 8192;         //  2,097,152
    unsigned char*  H2p  = (unsigned char*)(ws + off);  off += (size_t)2 * 8192;          //     16,384
    unsigned short* HoutB= (unsigned short*)(ws + off); off += (size_t)8192 * Hz * 2;     //  4,194,304
    float* row_sum       = (float*)(ws + off);          off += 8192 * 4;                  //     32,768
    unsigned* flags      = (unsigned*)(ws + off);       off += 64 * 4;                    //        256
    // total ~25.9 MiB

    hipMemsetAsync(row_sum, 0, 8192 * 4 + 64 * 4, stream);   // row_sum + flags
    hipMemsetAsync(out, 0, sizeof(float), stream);

    k_embed<<<8192, 64, 0, stream>>>(inp, emb, XS);
    k_wt<<<256, 256, 0, stream>>>(W1, W2, WGb);
    k_lstm7<<<32, 512, 0, stream>>>(XS, WGb, b1, b2, H1h, H2p,
                                    HoutB, flags, sw, SWT);
    k_gemm<<<dim3(64, 250), 256, 0, stream>>>((const __hip_bfloat16*)HoutB, SWT, sb, row_sum);
    k_loss<<<32, 256, 0, stream>>>((const __hip_bfloat16*)HoutB, SWT, sb, tgt, row_sum, out);
}